// Round 2
// 625.085 us; speedup vs baseline: 1.5964x; 1.5964x over previous
//
#include <hip/hip_runtime.h>
#include <hip/hip_bf16.h>
#include <math.h>

// Problem constants: B=64, N=512, H=768. fp32 in/out.
static constexpr int B_ = 64;
static constexpr int N_ = 512;
static constexpr int H_ = 768;

typedef float f32x16 __attribute__((ext_vector_type(16)));
typedef short bf16x8 __attribute__((ext_vector_type(8)));

static __device__ __forceinline__ f32x16 mfma32(bf16x8 a, bf16x8 b, f32x16 c) {
    return __builtin_amdgcn_mfma_f32_32x32x16_bf16(a, b, c, 0, 0, 0);
}

// hi/lo bf16 split via truncation. hi = trunc16(x); lo = trunc16(x - hi_f32).
// x - hi is exact (Sterbenz); total reconstruction err ~ |x| * 2^-16.
static __device__ __forceinline__ uint32_t pack_hi2(float f0, float f1) {
    uint32_t u0 = __float_as_uint(f0), u1 = __float_as_uint(f1);
    return (u1 & 0xFFFF0000u) | (u0 >> 16);
}
static __device__ __forceinline__ uint32_t pack_lo2(float f0, float f1) {
    uint32_t u0 = __float_as_uint(f0), u1 = __float_as_uint(f1);
    float l0 = f0 - __uint_as_float(u0 & 0xFFFF0000u);
    float l1 = f1 - __uint_as_float(u1 & 0xFFFF0000u);
    uint32_t v0 = __float_as_uint(l0), v1 = __float_as_uint(l1);
    return (v1 & 0xFFFF0000u) | (v0 >> 16);
}

// C/D 32x32 frag row for reg, half=lane>>5 (m74/m101-verified layout)
#define R32(reg, half) (((reg) & 3) + 8 * ((reg) >> 2) + 4 * (half))

// ---------------------------------------------------------------------------
// Kernel 1: Q = X @ W via hi/lo-split bf16 MFMA (3 products: hh, hl, lh;
// dropped ll term ~ |x||w|*2^-17, negligible vs downstream bf16 error).
// Block tile 128x128, 4 waves (2x2), wave tile 64x64, BK=32.
// A (X rows) staged hi/lo in LDS from coalesced float4 loads.
// B (W^T: [j][k]) staged hi/lo in LDS from j-coalesced scalar loads (W is
// L2-resident, 2.25 MB). Stride 40 u16 (80 B): uniform bank coverage for the
// uint2/uint4 writes and the b128 frag reads.
// Epilogue writes Q into d_out in the grouped-split format K2 consumes:
// per row, 96 groups of [16B hi-bf16 x8 | 16B lo-bf16 x8] = 3072 B/row.
// ---------------------------------------------------------------------------
__global__ __launch_bounds__(256, 2) void gemm_xw_mfma(const float* __restrict__ X,
                                                       const float* __restrict__ W,
                                                       uint32_t* __restrict__ C) {
    __shared__ __align__(16) unsigned short Ahi[128][40];
    __shared__ __align__(16) unsigned short Alo[128][40];
    __shared__ __align__(16) unsigned short Bhi[128][40];
    __shared__ __align__(16) unsigned short Blo[128][40];

    const int t    = threadIdx.x;
    const int w    = t >> 6;
    const int lane = t & 63;
    const int half = lane >> 5;
    const int ln   = lane & 31;
    const int wi   = w & 1;   // wave M-position (64-row slab)
    const int wh   = w >> 1;  // wave N-position (64-col slab)
    const int m0   = blockIdx.y * 128;
    const int n0   = blockIdx.x * 128;

    // A staging: thread owns (row = ar + u*32, float4 col = ac4), u = 0..3
    const int ar  = t >> 3;   // 0..31
    const int ac4 = t & 7;    // 0..7 -> k offset ac4*4
    // B staging: thread owns j-column bj, k range [bkb, bkb+16)
    const int bj  = t & 127;
    const int bkb = (t >> 7) * 16;

    f32x16 acc[2][2];
    f32x16 zf = {};
    #pragma unroll
    for (int is = 0; is < 2; ++is)
        #pragma unroll
        for (int hs = 0; hs < 2; ++hs) acc[is][hs] = zf;

    for (int k0 = 0; k0 < H_; k0 += 32) {
        // ---- issue global loads (overlap with previous tile's compute) ----
        float4 av[4];
        #pragma unroll
        for (int u = 0; u < 4; ++u)
            av[u] = *(const float4*)&X[(size_t)(m0 + ar + u * 32) * H_ + k0 + ac4 * 4];
        const float* wp = W + (size_t)(k0 + bkb) * H_ + n0 + bj;
        float wv[16];
        #pragma unroll
        for (int kk = 0; kk < 16; ++kk)
            wv[kk] = wp[(size_t)kk * H_];

        // ---- pack to hi/lo bf16 in registers ----
        uint2 ahp[4], alp[4];
        #pragma unroll
        for (int u = 0; u < 4; ++u) {
            ahp[u] = make_uint2(pack_hi2(av[u].x, av[u].y), pack_hi2(av[u].z, av[u].w));
            alp[u] = make_uint2(pack_lo2(av[u].x, av[u].y), pack_lo2(av[u].z, av[u].w));
        }
        uint4 bhp[2], blp[2];
        #pragma unroll
        for (int q = 0; q < 2; ++q) {
            const int b8 = q * 8;
            bhp[q] = make_uint4(pack_hi2(wv[b8 + 0], wv[b8 + 1]), pack_hi2(wv[b8 + 2], wv[b8 + 3]),
                                pack_hi2(wv[b8 + 4], wv[b8 + 5]), pack_hi2(wv[b8 + 6], wv[b8 + 7]));
            blp[q] = make_uint4(pack_lo2(wv[b8 + 0], wv[b8 + 1]), pack_lo2(wv[b8 + 2], wv[b8 + 3]),
                                pack_lo2(wv[b8 + 4], wv[b8 + 5]), pack_lo2(wv[b8 + 6], wv[b8 + 7]));
        }

        __syncthreads();   // previous tile's readers done
        #pragma unroll
        for (int u = 0; u < 4; ++u) {
            *(uint2*)&Ahi[ar + u * 32][ac4 * 4] = ahp[u];
            *(uint2*)&Alo[ar + u * 32][ac4 * 4] = alp[u];
        }
        #pragma unroll
        for (int q = 0; q < 2; ++q) {
            *(uint4*)&Bhi[bj][bkb + q * 8] = bhp[q];
            *(uint4*)&Blo[bj][bkb + q * 8] = blp[q];
        }
        __syncthreads();   // tile staged

        // ---- MFMA inner loop: 2 k16 steps, 12 MFMA each per wave ----
        #pragma unroll
        for (int ks = 0; ks < 2; ++ks) {
            const int koff = ks * 16 + half * 8;
            bf16x8 ah[2], al[2], bh[2], bl[2];
            #pragma unroll
            for (int is = 0; is < 2; ++is) {
                ah[is] = *(const bf16x8*)&Ahi[wi * 64 + is * 32 + ln][koff];
                al[is] = *(const bf16x8*)&Alo[wi * 64 + is * 32 + ln][koff];
            }
            #pragma unroll
            for (int hs = 0; hs < 2; ++hs) {
                bh[hs] = *(const bf16x8*)&Bhi[wh * 64 + hs * 32 + ln][koff];
                bl[hs] = *(const bf16x8*)&Blo[wh * 64 + hs * 32 + ln][koff];
            }
            #pragma unroll
            for (int is = 0; is < 2; ++is)
                #pragma unroll
                for (int hs = 0; hs < 2; ++hs) {
                    acc[is][hs] = mfma32(ah[is], bh[hs], acc[is][hs]);
                    acc[is][hs] = mfma32(ah[is], bl[hs], acc[is][hs]);
                    acc[is][hs] = mfma32(al[is], bh[hs], acc[is][hs]);
                }
        }
    }

    // ---- epilogue: fp32 acc -> grouped hi/lo split format ----
    // Lane ln holds column gj = n0 + wh*64 + hs*32 + ln. Pair even/odd columns
    // via shfl_xor(1); even lanes write the 2-col hi u32 and lo u32.
    #pragma unroll
    for (int is = 0; is < 2; ++is)
        #pragma unroll
        for (int hs = 0; hs < 2; ++hs)
            #pragma unroll
            for (int reg = 0; reg < 16; ++reg) {
                float v  = acc[is][hs][reg];
                float v1 = __shfl_xor(v, 1);
                if ((ln & 1) == 0) {
                    const int gi = m0 + wi * 64 + is * 32 + R32(reg, half);
                    const int gj = n0 + wh * 64 + hs * 32 + ln;   // even
                    uint32_t* orow = C + (size_t)gi * H_;         // 768 u32/row
                    const int g = gj >> 3;
                    const int p = (gj >> 1) & 3;
                    orow[g * 8 + p]     = pack_hi2(v, v1);
                    orow[g * 8 + 4 + p] = pack_lo2(v, v1);
                }
            }
}

// ---------------------------------------------------------------------------
// Kernel 2: scores + softmax -> normalized P (bf16) in ws.
// Block = 64 i-rows (grid 8 x 64), 4 waves. 3-pass hi/lo split MFMA 32x32x16.
// j staged 128 rows x 96-k chunks (hi+lo bf16, padded stride 104).
// Wave w owns j columns {jb*128 + w*32 + (0..31)}. Per-wave softmax partials
// combined across waves via small LDS arrays; P normalized before store.
// ---------------------------------------------------------------------------
__global__ __launch_bounds__(256, 2) void attn_scores(const float* __restrict__ X,
                                                      const uint32_t* __restrict__ Q32,
                                                      const float* __restrict__ bias_p,
                                                      __hip_bfloat16* __restrict__ P) {
    __shared__ __align__(16) unsigned short Khi[128][104];
    __shared__ __align__(16) unsigned short Klo[128][104];
    __shared__ float smax[4][64];
    __shared__ float ssum[4][64];
    __shared__ float sscale[4][64];

    const int t    = threadIdx.x;
    const int w    = t >> 6;
    const int lane = t & 63;
    const int half = lane >> 5;
    const int ln   = lane & 31;
    const int b    = blockIdx.y;
    const int I0   = blockIdx.x * 64;
    const float bias = bias_p[0];

    const float* xb = X + (size_t)b * N_ * H_;

    f32x16 acc[2][4];
    f32x16 zf = {};
    #pragma unroll
    for (int is = 0; is < 2; ++is)
        #pragma unroll
        for (int jb = 0; jb < 4; ++jb) acc[is][jb] = zf;

    for (int jb = 0; jb < 4; ++jb) {
        for (int kph = 0; kph < 8; ++kph) {
            __syncthreads();
            // stage 128 j-rows x 96 k (hi+lo) from fp32 global
            #pragma unroll
            for (int u = 0; u < 12; ++u) {
                int idx = t + 256 * u;
                int r   = idx / 24;
                int c4  = idx - r * 24;
                float4 f = *(const float4*)&xb[(size_t)(jb * 128 + r) * H_ + kph * 96 + c4 * 4];
                uint32_t h0 = pack_hi2(f.x, f.y), h1 = pack_hi2(f.z, f.w);
                uint32_t l0 = pack_lo2(f.x, f.y), l1 = pack_lo2(f.z, f.w);
                *(uint2*)&Khi[r][c4 * 4] = make_uint2(h0, h1);
                *(uint2*)&Klo[r][c4 * 4] = make_uint2(l0, l1);
            }
            __syncthreads();
            #pragma unroll
            for (int ks = 0; ks < 6; ++ks) {
                // Q A-frags from grouped-split global (L1-resident within kph)
                const int kgrp = kph * 12 + ks * 2 + half;
                bf16x8 qh[2], ql[2];
                #pragma unroll
                for (int is = 0; is < 2; ++is) {
                    const uint32_t* qr =
                        Q32 + ((size_t)b * N_ + I0 + is * 32 + ln) * H_ + (size_t)kgrp * 8;
                    qh[is] = *(const bf16x8*)(qr);
                    ql[is] = *(const bf16x8*)(qr + 4);
                }
                // K B-frags from LDS
                const int koff = ks * 16 + half * 8;
                bf16x8 kh = *(const bf16x8*)&Khi[w * 32 + ln][koff];
                bf16x8 kl = *(const bf16x8*)&Klo[w * 32 + ln][koff];
                #pragma unroll
                for (int is = 0; is < 2; ++is) {
                    acc[is][jb] = mfma32(qh[is], kh, acc[is][jb]);
                    acc[is][jb] = mfma32(qh[is], kl, acc[is][jb]);
                    acc[is][jb] = mfma32(ql[is], kh, acc[is][jb]);
                }
            }
        }
    }

    // bias + diagonal zero (ref zeroes scores at i==j AFTER bias, pre-softmax)
    const int gj = /* this lane's global j col per jb: */ w * 32 + ln;  // + jb*128
    #pragma unroll
    for (int is = 0; is < 2; ++is)
        #pragma unroll
        for (int jb = 0; jb < 4; ++jb)
            #pragma unroll
            for (int reg = 0; reg < 16; ++reg) {
                float v = acc[is][jb][reg] + bias;
                int gi = I0 + is * 32 + R32(reg, half);
                if (gi == jb * 128 + gj) v = 0.0f;
                acc[is][jb][reg] = v;
            }

    // wave-local row max over this wave's 128 j
    float mrow[2][16];
    #pragma unroll
    for (int is = 0; is < 2; ++is)
        #pragma unroll
        for (int reg = 0; reg < 16; ++reg) {
            float m = acc[is][0][reg];
            #pragma unroll
            for (int jb = 1; jb < 4; ++jb) m = fmaxf(m, acc[is][jb][reg]);
            #pragma unroll
            for (int d = 1; d < 32; d <<= 1) m = fmaxf(m, __shfl_xor(m, d));
            mrow[is][reg] = m;
            if (ln == 0) smax[w][is * 32 + R32(reg, half)] = m;
        }

    // exp + wave-local row sum
    #pragma unroll
    for (int is = 0; is < 2; ++is)
        #pragma unroll
        for (int reg = 0; reg < 16; ++reg) {
            float s = 0.f;
            #pragma unroll
            for (int jb = 0; jb < 4; ++jb) {
                float e = __expf(acc[is][jb][reg] - mrow[is][reg]);
                acc[is][jb][reg] = e;
                s += e;
            }
            #pragma unroll
            for (int d = 1; d < 32; d <<= 1) s += __shfl_xor(s, d);
            if (ln == 0) ssum[w][is * 32 + R32(reg, half)] = s;
        }
    __syncthreads();

    // combine across the 4 waves; sscale[w][row] = exp(m_w - M) / L
    if (t < 64) {
        float M = smax[0][t];
        #pragma unroll
        for (int w2 = 1; w2 < 4; ++w2) M = fmaxf(M, smax[w2][t]);
        float L = 0.f;
        #pragma unroll
        for (int w2 = 0; w2 < 4; ++w2) L += ssum[w2][t] * __expf(smax[w2][t] - M);
        float invL = 1.0f / L;
        #pragma unroll
        for (int w2 = 0; w2 < 4; ++w2) sscale[w2][t] = __expf(smax[w2][t] - M) * invL;
    }
    __syncthreads();

    // store normalized P (bf16) to ws
    __hip_bfloat16* Pb = P + (size_t)b * N_ * N_;
    #pragma unroll
    for (int is = 0; is < 2; ++is)
        #pragma unroll
        for (int reg = 0; reg < 16; ++reg) {
            int row = is * 32 + R32(reg, half);
            float sc = sscale[w][row];
            #pragma unroll
            for (int jb = 0; jb < 4; ++jb) {
                float p = acc[is][jb][reg] * sc;
                Pb[(size_t)(I0 + row) * N_ + jb * 128 + w * 32 + ln] = __float2bfloat16(p);
            }
        }
}

// ---------------------------------------------------------------------------
// Kernel 3: O = P (bf16) @ X (bf16 RNE), MFMA 32x32x16. Block tile 128i x 256h,
// wave tile 64i x 128h (2x4 frags -> 42 flop/LDS-byte, compute-bound).
// X tile transposed into LDS (h-major, stride 40 bf16 -> bank-scrambled).
// ---------------------------------------------------------------------------
__global__ __launch_bounds__(256, 2) void pv_gemm(const float* __restrict__ X,
                                                  const __hip_bfloat16* __restrict__ P,
                                                  float* __restrict__ O) {
    __shared__ __align__(16) unsigned short Pt[128][40];
    __shared__ __align__(16) unsigned short Vt[256][40];

    const int t    = threadIdx.x;
    const int w    = t >> 6;
    const int lane = t & 63;
    const int half = lane >> 5;
    const int ln   = lane & 31;
    const int wi   = w & 1;
    const int wh   = w >> 1;
    const int b    = blockIdx.z;
    const int I0   = blockIdx.y * 128;
    const int H0   = blockIdx.x * 256;

    const unsigned short* Pb = (const unsigned short*)P + (size_t)b * N_ * N_;
    const float* xb = X + (size_t)b * N_ * H_;

    f32x16 acc[2][4];
    f32x16 zf = {};
    #pragma unroll
    for (int is = 0; is < 2; ++is)
        #pragma unroll
        for (int hs = 0; hs < 4; ++hs) acc[is][hs] = zf;

    for (int j0 = 0; j0 < N_; j0 += 32) {
        __syncthreads();
        // stage P tile 128 x 32 (row-major, already bf16)
        #pragma unroll
        for (int u = 0; u < 2; ++u) {
            int idx = t + 256 * u;
            int r   = idx >> 2;
            int c8  = idx & 3;
            uint4 v = *(const uint4*)&Pb[(size_t)(I0 + r) * N_ + j0 + c8 * 8];
            *(uint4*)&Pt[r][c8 * 8] = v;
        }
        // stage V tile transposed: thread t owns h-col H0+t, walks 32 j-rows
        {
            const float* xc = xb + (size_t)j0 * H_ + H0 + t;
            #pragma unroll
            for (int jj = 0; jj < 32; jj += 2) {
                float f0 = xc[(size_t)jj * H_];
                float f1 = xc[(size_t)(jj + 1) * H_];
                __hip_bfloat16 b0 = __float2bfloat16(f0);
                __hip_bfloat16 b1 = __float2bfloat16(f1);
                unsigned short u0, u1;
                __builtin_memcpy(&u0, &b0, 2);
                __builtin_memcpy(&u1, &b1, 2);
                *(uint32_t*)&Vt[t][jj] = ((uint32_t)u1 << 16) | u0;
            }
        }
        __syncthreads();
        #pragma unroll
        for (int ks = 0; ks < 2; ++ks) {
            const int koff = ks * 16 + half * 8;
            bf16x8 a[2], v[4];
            #pragma unroll
            for (int is = 0; is < 2; ++is)
                a[is] = *(const bf16x8*)&Pt[wi * 64 + is * 32 + ln][koff];
            #pragma unroll
            for (int hs = 0; hs < 4; ++hs)
                v[hs] = *(const bf16x8*)&Vt[wh * 128 + hs * 32 + ln][koff];
            #pragma unroll
            for (int is = 0; is < 2; ++is)
                #pragma unroll
                for (int hs = 0; hs < 4; ++hs)
                    acc[is][hs] = mfma32(a[is], v[hs], acc[is][hs]);
        }
    }

    float* Ob = O + (size_t)b * N_ * H_;
    #pragma unroll
    for (int is = 0; is < 2; ++is)
        #pragma unroll
        for (int hs = 0; hs < 4; ++hs)
            #pragma unroll
            for (int reg = 0; reg < 16; ++reg) {
                int row = I0 + wi * 64 + is * 32 + R32(reg, half);
                int col = H0 + wh * 128 + hs * 32 + ln;
                Ob[(size_t)row * H_ + col] = acc[is][hs][reg];
            }
}

extern "C" void kernel_launch(void* const* d_in, const int* in_sizes, int n_in,
                              void* d_out, int out_size, void* d_ws, size_t ws_size,
                              hipStream_t stream) {
    const float* x    = (const float*)d_in[0];   // [B,N,H]
    const float* W    = (const float*)d_in[1];   // [H,H]
    const float* bias = (const float*)d_in[2];   // [1]

    // K1: d_out <- split(X @ W) via hi/lo bf16 MFMA (grouped format, fp32 footprint)
    gemm_xw_mfma<<<dim3(H_ / 128, (B_ * N_) / 128), 256, 0, stream>>>(
        x, W, (uint32_t*)d_out);
    // K2: ws <- normalized softmax(Q . X^T + bias, diag->0)  as bf16 [B,N,N]
    attn_scores<<<dim3(N_ / 64, B_), 256, 0, stream>>>(
        x, (const uint32_t*)d_out, bias, (__hip_bfloat16*)d_ws);
    // K3: d_out <- P @ X  (fp32 result)
    pv_gemm<<<dim3(H_ / 256, N_ / 128, B_), 256, 0, stream>>>(
        x, (const __hip_bfloat16*)d_ws, (float*)d_out);
}

// Round 3
// 551.394 us; speedup vs baseline: 1.8098x; 1.1336x over previous
//
#include <hip/hip_runtime.h>
#include <hip/hip_bf16.h>
#include <math.h>

// Problem constants: B=64, N=512, H=768. fp32 in/out.
static constexpr int B_ = 64;
static constexpr int N_ = 512;
static constexpr int H_ = 768;

typedef float f32x16 __attribute__((ext_vector_type(16)));
typedef short bf16x8 __attribute__((ext_vector_type(8)));

static __device__ __forceinline__ f32x16 mfma32(bf16x8 a, bf16x8 b, f32x16 c) {
    return __builtin_amdgcn_mfma_f32_32x32x16_bf16(a, b, c, 0, 0, 0);
}

// hi/lo bf16 split via truncation. hi = trunc16(x); lo = trunc16(x - hi_f32).
// x - hi is exact (Sterbenz); total reconstruction err ~ |x| * 2^-16.
static __device__ __forceinline__ uint32_t pack_hi2(float f0, float f1) {
    uint32_t u0 = __float_as_uint(f0), u1 = __float_as_uint(f1);
    return (u1 & 0xFFFF0000u) | (u0 >> 16);
}
static __device__ __forceinline__ uint32_t pack_lo2(float f0, float f1) {
    uint32_t u0 = __float_as_uint(f0), u1 = __float_as_uint(f1);
    float l0 = f0 - __uint_as_float(u0 & 0xFFFF0000u);
    float l1 = f1 - __uint_as_float(u1 & 0xFFFF0000u);
    uint32_t v0 = __float_as_uint(l0), v1 = __float_as_uint(l1);
    return (v1 & 0xFFFF0000u) | (v0 >> 16);
}

// C/D 32x32 frag row for reg, half=lane>>5 (m74/m101-verified layout)
#define R32(reg, half) (((reg) & 3) + 8 * ((reg) >> 2) + 4 * (half))

// ---------------------------------------------------------------------------
// Kernel 1: Q = X @ W via hi/lo-split bf16 MFMA (3 products: hh, hl, lh).
// Block tile 128x128, 4 waves (2x2), wave tile 64x64, BK=32.
// XCD swizzle: 1D grid 1536; same-row-slab blocks (6 n-tiles sharing a
// 128-row X slab = 384 KB) co-located on one XCD -> X slab L2-hits.
//   l = xcd + 8*(nx + 6*yq), xcd=y%8, yq=y/8  (bijective: 8*6*32 = 1536)
// Epilogue writes Q into d_out in the grouped-split format K2 consumes.
// ---------------------------------------------------------------------------
__global__ __launch_bounds__(256, 2) void gemm_xw_mfma(const float* __restrict__ X,
                                                       const float* __restrict__ W,
                                                       uint32_t* __restrict__ C) {
    __shared__ __align__(16) unsigned short Ahi[128][40];
    __shared__ __align__(16) unsigned short Alo[128][40];
    __shared__ __align__(16) unsigned short Bhi[128][40];
    __shared__ __align__(16) unsigned short Blo[128][40];

    const int t    = threadIdx.x;
    const int w    = t >> 6;
    const int lane = t & 63;
    const int half = lane >> 5;
    const int ln   = lane & 31;
    const int wi   = w & 1;   // wave M-position (64-row slab)
    const int wh   = w >> 1;  // wave N-position (64-col slab)

    // XCD-aware decode: same M-slab -> same XCD
    const int l   = blockIdx.x;       // 0..1535
    const int xcd = l & 7;
    const int r   = l >> 3;           // 0..191
    const int nx  = r % 6;            // N-tile 0..5
    const int yq  = r / 6;            // 0..31
    const int m0  = (xcd + 8 * yq) * 128;
    const int n0  = nx * 128;

    // A staging: thread owns (row = ar + u*32, float4 col = ac4), u = 0..3
    const int ar  = t >> 3;   // 0..31
    const int ac4 = t & 7;    // 0..7 -> k offset ac4*4
    // B staging: thread owns j-column bj, k range [bkb, bkb+16)
    const int bj  = t & 127;
    const int bkb = (t >> 7) * 16;

    f32x16 acc[2][2];
    f32x16 zf = {};
    #pragma unroll
    for (int is = 0; is < 2; ++is)
        #pragma unroll
        for (int hs = 0; hs < 2; ++hs) acc[is][hs] = zf;

    for (int k0 = 0; k0 < H_; k0 += 32) {
        // ---- issue global loads (overlap with previous tile's compute) ----
        float4 av[4];
        #pragma unroll
        for (int u = 0; u < 4; ++u)
            av[u] = *(const float4*)&X[(size_t)(m0 + ar + u * 32) * H_ + k0 + ac4 * 4];
        const float* wp = W + (size_t)(k0 + bkb) * H_ + n0 + bj;
        float wv[16];
        #pragma unroll
        for (int kk = 0; kk < 16; ++kk)
            wv[kk] = wp[(size_t)kk * H_];

        // ---- pack to hi/lo bf16 in registers ----
        uint2 ahp[4], alp[4];
        #pragma unroll
        for (int u = 0; u < 4; ++u) {
            ahp[u] = make_uint2(pack_hi2(av[u].x, av[u].y), pack_hi2(av[u].z, av[u].w));
            alp[u] = make_uint2(pack_lo2(av[u].x, av[u].y), pack_lo2(av[u].z, av[u].w));
        }
        uint4 bhp[2], blp[2];
        #pragma unroll
        for (int q = 0; q < 2; ++q) {
            const int b8 = q * 8;
            bhp[q] = make_uint4(pack_hi2(wv[b8 + 0], wv[b8 + 1]), pack_hi2(wv[b8 + 2], wv[b8 + 3]),
                                pack_hi2(wv[b8 + 4], wv[b8 + 5]), pack_hi2(wv[b8 + 6], wv[b8 + 7]));
            blp[q] = make_uint4(pack_lo2(wv[b8 + 0], wv[b8 + 1]), pack_lo2(wv[b8 + 2], wv[b8 + 3]),
                                pack_lo2(wv[b8 + 4], wv[b8 + 5]), pack_lo2(wv[b8 + 6], wv[b8 + 7]));
        }

        __syncthreads();   // previous tile's readers done
        #pragma unroll
        for (int u = 0; u < 4; ++u) {
            *(uint2*)&Ahi[ar + u * 32][ac4 * 4] = ahp[u];
            *(uint2*)&Alo[ar + u * 32][ac4 * 4] = alp[u];
        }
        #pragma unroll
        for (int q = 0; q < 2; ++q) {
            *(uint4*)&Bhi[bj][bkb + q * 8] = bhp[q];
            *(uint4*)&Blo[bj][bkb + q * 8] = blp[q];
        }
        __syncthreads();   // tile staged

        // ---- MFMA inner loop: 2 k16 steps, 12 MFMA each per wave ----
        #pragma unroll
        for (int ks = 0; ks < 2; ++ks) {
            const int koff = ks * 16 + half * 8;
            bf16x8 ah[2], al[2], bh[2], bl[2];
            #pragma unroll
            for (int is = 0; is < 2; ++is) {
                ah[is] = *(const bf16x8*)&Ahi[wi * 64 + is * 32 + ln][koff];
                al[is] = *(const bf16x8*)&Alo[wi * 64 + is * 32 + ln][koff];
            }
            #pragma unroll
            for (int hs = 0; hs < 2; ++hs) {
                bh[hs] = *(const bf16x8*)&Bhi[wh * 64 + hs * 32 + ln][koff];
                bl[hs] = *(const bf16x8*)&Blo[wh * 64 + hs * 32 + ln][koff];
            }
            #pragma unroll
            for (int is = 0; is < 2; ++is)
                #pragma unroll
                for (int hs = 0; hs < 2; ++hs) {
                    acc[is][hs] = mfma32(ah[is], bh[hs], acc[is][hs]);
                    acc[is][hs] = mfma32(ah[is], bl[hs], acc[is][hs]);
                    acc[is][hs] = mfma32(al[is], bh[hs], acc[is][hs]);
                }
        }
    }

    // ---- epilogue: fp32 acc -> grouped hi/lo split format ----
    #pragma unroll
    for (int is = 0; is < 2; ++is)
        #pragma unroll
        for (int hs = 0; hs < 2; ++hs)
            #pragma unroll
            for (int reg = 0; reg < 16; ++reg) {
                float v  = acc[is][hs][reg];
                float v1 = __shfl_xor(v, 1);
                if ((ln & 1) == 0) {
                    const int gi = m0 + wi * 64 + is * 32 + R32(reg, half);
                    const int gj = n0 + wh * 64 + hs * 32 + ln;   // even
                    uint32_t* orow = C + (size_t)gi * H_;         // 768 u32/row
                    const int g = gj >> 3;
                    const int p = (gj >> 1) & 3;
                    orow[g * 8 + p]     = pack_hi2(v, v1);
                    orow[g * 8 + 4 + p] = pack_lo2(v, v1);
                }
            }
}

// ---------------------------------------------------------------------------
// Kernel 2: scores + softmax -> normalized P (bf16) in ws.
// Block = 64 i-rows, 4 waves. 3-pass hi/lo split MFMA 32x32x16.
// XCD swizzle: 1D grid 512; the 8 i-tile blocks of a batch co-located on one
// XCD -> the per-phase 48 KB X j-slab is fetched once per XCD, L2-hit for the
// other 7 blocks (they run in lockstep; phase working set ~392 KB << 4 MB L2).
//   l = (b%8) + 8*(ix + 8*(b/8))   (bijective: 8*8*8 = 512)
// ---------------------------------------------------------------------------
__global__ __launch_bounds__(256, 2) void attn_scores(const float* __restrict__ X,
                                                      const uint32_t* __restrict__ Q32,
                                                      const float* __restrict__ bias_p,
                                                      __hip_bfloat16* __restrict__ P) {
    __shared__ __align__(16) unsigned short Khi[128][104];
    __shared__ __align__(16) unsigned short Klo[128][104];
    __shared__ float smax[4][64];
    __shared__ float ssum[4][64];
    __shared__ float sscale[4][64];

    const int t    = threadIdx.x;
    const int w    = t >> 6;
    const int lane = t & 63;
    const int half = lane >> 5;
    const int ln   = lane & 31;

    // XCD-aware decode: same batch -> same XCD
    const int l  = blockIdx.x;        // 0..511
    const int q  = l >> 3;            // 0..63
    const int b  = (l & 7) + 8 * (q >> 3);
    const int I0 = (q & 7) * 64;
    const float bias = bias_p[0];

    const float* xb = X + (size_t)b * N_ * H_;

    f32x16 acc[2][4];
    f32x16 zf = {};
    #pragma unroll
    for (int is = 0; is < 2; ++is)
        #pragma unroll
        for (int jb = 0; jb < 4; ++jb) acc[is][jb] = zf;

    for (int jb = 0; jb < 4; ++jb) {
        for (int kph = 0; kph < 8; ++kph) {
            __syncthreads();
            // stage 128 j-rows x 96 k (hi+lo) from fp32 global
            #pragma unroll
            for (int u = 0; u < 12; ++u) {
                int idx = t + 256 * u;
                int r   = idx / 24;
                int c4  = idx - r * 24;
                float4 f = *(const float4*)&xb[(size_t)(jb * 128 + r) * H_ + kph * 96 + c4 * 4];
                uint32_t h0 = pack_hi2(f.x, f.y), h1 = pack_hi2(f.z, f.w);
                uint32_t l0 = pack_lo2(f.x, f.y), l1 = pack_lo2(f.z, f.w);
                *(uint2*)&Khi[r][c4 * 4] = make_uint2(h0, h1);
                *(uint2*)&Klo[r][c4 * 4] = make_uint2(l0, l1);
            }
            __syncthreads();
            #pragma unroll
            for (int ks = 0; ks < 6; ++ks) {
                // Q A-frags from grouped-split global (L1-resident within kph)
                const int kgrp = kph * 12 + ks * 2 + half;
                bf16x8 qh[2], ql[2];
                #pragma unroll
                for (int is = 0; is < 2; ++is) {
                    const uint32_t* qr =
                        Q32 + ((size_t)b * N_ + I0 + is * 32 + ln) * H_ + (size_t)kgrp * 8;
                    qh[is] = *(const bf16x8*)(qr);
                    ql[is] = *(const bf16x8*)(qr + 4);
                }
                // K B-frags from LDS
                const int koff = ks * 16 + half * 8;
                bf16x8 kh = *(const bf16x8*)&Khi[w * 32 + ln][koff];
                bf16x8 kl = *(const bf16x8*)&Klo[w * 32 + ln][koff];
                #pragma unroll
                for (int is = 0; is < 2; ++is) {
                    acc[is][jb] = mfma32(qh[is], kh, acc[is][jb]);
                    acc[is][jb] = mfma32(qh[is], kl, acc[is][jb]);
                    acc[is][jb] = mfma32(ql[is], kh, acc[is][jb]);
                }
            }
        }
    }

    // bias + diagonal zero (ref zeroes scores at i==j AFTER bias, pre-softmax)
    const int gj = w * 32 + ln;  // + jb*128
    #pragma unroll
    for (int is = 0; is < 2; ++is)
        #pragma unroll
        for (int jb = 0; jb < 4; ++jb)
            #pragma unroll
            for (int reg = 0; reg < 16; ++reg) {
                float v = acc[is][jb][reg] + bias;
                int gi = I0 + is * 32 + R32(reg, half);
                if (gi == jb * 128 + gj) v = 0.0f;
                acc[is][jb][reg] = v;
            }

    // wave-local row max over this wave's 128 j
    float mrow[2][16];
    #pragma unroll
    for (int is = 0; is < 2; ++is)
        #pragma unroll
        for (int reg = 0; reg < 16; ++reg) {
            float m = acc[is][0][reg];
            #pragma unroll
            for (int jb = 1; jb < 4; ++jb) m = fmaxf(m, acc[is][jb][reg]);
            #pragma unroll
            for (int d = 1; d < 32; d <<= 1) m = fmaxf(m, __shfl_xor(m, d));
            mrow[is][reg] = m;
            if (ln == 0) smax[w][is * 32 + R32(reg, half)] = m;
        }

    // exp + wave-local row sum
    #pragma unroll
    for (int is = 0; is < 2; ++is)
        #pragma unroll
        for (int reg = 0; reg < 16; ++reg) {
            float s = 0.f;
            #pragma unroll
            for (int jb = 0; jb < 4; ++jb) {
                float e = __expf(acc[is][jb][reg] - mrow[is][reg]);
                acc[is][jb][reg] = e;
                s += e;
            }
            #pragma unroll
            for (int d = 1; d < 32; d <<= 1) s += __shfl_xor(s, d);
            if (ln == 0) ssum[w][is * 32 + R32(reg, half)] = s;
        }
    __syncthreads();

    // combine across the 4 waves; sscale[w][row] = exp(m_w - M) / L
    if (t < 64) {
        float M = smax[0][t];
        #pragma unroll
        for (int w2 = 1; w2 < 4; ++w2) M = fmaxf(M, smax[w2][t]);
        float L = 0.f;
        #pragma unroll
        for (int w2 = 0; w2 < 4; ++w2) L += ssum[w2][t] * __expf(smax[w2][t] - M);
        float invL = 1.0f / L;
        #pragma unroll
        for (int w2 = 0; w2 < 4; ++w2) sscale[w2][t] = __expf(smax[w2][t] - M) * invL;
    }
    __syncthreads();

    // store normalized P (bf16) to ws
    __hip_bfloat16* Pb = P + (size_t)b * N_ * N_;
    #pragma unroll
    for (int is = 0; is < 2; ++is)
        #pragma unroll
        for (int reg = 0; reg < 16; ++reg) {
            int row = is * 32 + R32(reg, half);
            float sc = sscale[w][row];
            #pragma unroll
            for (int jb = 0; jb < 4; ++jb) {
                float p = acc[is][jb][reg] * sc;
                Pb[(size_t)(I0 + row) * N_ + jb * 128 + w * 32 + ln] = __float2bfloat16(p);
            }
        }
}

// ---------------------------------------------------------------------------
// Kernel 3: O = P (bf16) @ X (bf16 RNE), MFMA 32x32x16. Block tile 128i x 256h,
// wave tile 64i x 128h. X tile transposed into LDS (h-major, stride 40 bf16).
// XCD swizzle: 1D grid 768; the 12 blocks of a batch (3 H-tiles x 4 I-tiles,
// sharing V = X[b] and P[b]) co-located on one XCD.
//   l = (b%8) + 8*(inner + 12*(b/8)), inner = hx + 3*iy  (bijective: 8*12*8)
// ---------------------------------------------------------------------------
__global__ __launch_bounds__(256, 2) void pv_gemm(const float* __restrict__ X,
                                                  const __hip_bfloat16* __restrict__ P,
                                                  float* __restrict__ O) {
    __shared__ __align__(16) unsigned short Pt[128][40];
    __shared__ __align__(16) unsigned short Vt[256][40];

    const int t    = threadIdx.x;
    const int w    = t >> 6;
    const int lane = t & 63;
    const int half = lane >> 5;
    const int ln   = lane & 31;
    const int wi   = w & 1;
    const int wh   = w >> 1;

    // XCD-aware decode: same batch -> same XCD
    const int l     = blockIdx.x;     // 0..767
    const int r     = l >> 3;         // 0..95
    const int inner = r % 12;
    const int b     = (l & 7) + 8 * (r / 12);
    const int H0    = (inner % 3) * 256;
    const int I0    = (inner / 3) * 128;

    const unsigned short* Pb = (const unsigned short*)P + (size_t)b * N_ * N_;
    const float* xb = X + (size_t)b * N_ * H_;

    f32x16 acc[2][4];
    f32x16 zf = {};
    #pragma unroll
    for (int is = 0; is < 2; ++is)
        #pragma unroll
        for (int hs = 0; hs < 4; ++hs) acc[is][hs] = zf;

    for (int j0 = 0; j0 < N_; j0 += 32) {
        __syncthreads();
        // stage P tile 128 x 32 (row-major, already bf16)
        #pragma unroll
        for (int u = 0; u < 2; ++u) {
            int idx = t + 256 * u;
            int rr  = idx >> 2;
            int c8  = idx & 3;
            uint4 v = *(const uint4*)&Pb[(size_t)(I0 + rr) * N_ + j0 + c8 * 8];
            *(uint4*)&Pt[rr][c8 * 8] = v;
        }
        // stage V tile transposed: thread t owns h-col H0+t, walks 32 j-rows
        {
            const float* xc = xb + (size_t)j0 * H_ + H0 + t;
            #pragma unroll
            for (int jj = 0; jj < 32; jj += 2) {
                float f0 = xc[(size_t)jj * H_];
                float f1 = xc[(size_t)(jj + 1) * H_];
                __hip_bfloat16 b0 = __float2bfloat16(f0);
                __hip_bfloat16 b1 = __float2bfloat16(f1);
                unsigned short u0, u1;
                __builtin_memcpy(&u0, &b0, 2);
                __builtin_memcpy(&u1, &b1, 2);
                *(uint32_t*)&Vt[t][jj] = ((uint32_t)u1 << 16) | u0;
            }
        }
        __syncthreads();
        #pragma unroll
        for (int ks = 0; ks < 2; ++ks) {
            const int koff = ks * 16 + half * 8;
            bf16x8 a[2], v[4];
            #pragma unroll
            for (int is = 0; is < 2; ++is)
                a[is] = *(const bf16x8*)&Pt[wi * 64 + is * 32 + ln][koff];
            #pragma unroll
            for (int hs = 0; hs < 4; ++hs)
                v[hs] = *(const bf16x8*)&Vt[wh * 128 + hs * 32 + ln][koff];
            #pragma unroll
            for (int is = 0; is < 2; ++is)
                #pragma unroll
                for (int hs = 0; hs < 4; ++hs)
                    acc[is][hs] = mfma32(a[is], v[hs], acc[is][hs]);
        }
    }

    float* Ob = O + (size_t)b * N_ * H_;
    #pragma unroll
    for (int is = 0; is < 2; ++is)
        #pragma unroll
        for (int hs = 0; hs < 4; ++hs)
            #pragma unroll
            for (int reg = 0; reg < 16; ++reg) {
                int row = I0 + wi * 64 + is * 32 + R32(reg, half);
                int col = H0 + wh * 128 + hs * 32 + ln;
                Ob[(size_t)row * H_ + col] = acc[is][hs][reg];
            }
}

extern "C" void kernel_launch(void* const* d_in, const int* in_sizes, int n_in,
                              void* d_out, int out_size, void* d_ws, size_t ws_size,
                              hipStream_t stream) {
    const float* x    = (const float*)d_in[0];   // [B,N,H]
    const float* W    = (const float*)d_in[1];   // [H,H]
    const float* bias = (const float*)d_in[2];   // [1]

    // K1: d_out <- split(X @ W) via hi/lo bf16 MFMA (grouped format, fp32 footprint)
    gemm_xw_mfma<<<dim3(1536), 256, 0, stream>>>(x, W, (uint32_t*)d_out);
    // K2: ws <- normalized softmax(Q . X^T + bias, diag->0)  as bf16 [B,N,N]
    attn_scores<<<dim3(512), 256, 0, stream>>>(
        x, (const uint32_t*)d_out, bias, (__hip_bfloat16*)d_ws);
    // K3: d_out <- P @ X  (fp32 result)
    pv_gemm<<<dim3(768), 256, 0, stream>>>(
        x, (const __hip_bfloat16*)d_ws, (float*)d_out);
}

// Round 4
// 431.417 us; speedup vs baseline: 2.3131x; 1.2781x over previous
//
#include <hip/hip_runtime.h>
#include <hip/hip_bf16.h>
#include <math.h>

// Problem constants: B=64, N=512, H=768. fp32 in/out.
static constexpr int B_ = 64;
static constexpr int N_ = 512;
static constexpr int H_ = 768;

typedef float f32x16 __attribute__((ext_vector_type(16)));
typedef short bf16x8 __attribute__((ext_vector_type(8)));

static __device__ __forceinline__ f32x16 mfma32(bf16x8 a, bf16x8 b, f32x16 c) {
    return __builtin_amdgcn_mfma_f32_32x32x16_bf16(a, b, c, 0, 0, 0);
}

// hi/lo bf16 split via truncation. hi = trunc16(x); lo = trunc16(x - hi_f32).
// x - hi is exact (Sterbenz); total reconstruction err ~ |x| * 2^-16.
static __device__ __forceinline__ uint32_t pack_hi2(float f0, float f1) {
    uint32_t u0 = __float_as_uint(f0), u1 = __float_as_uint(f1);
    return (u1 & 0xFFFF0000u) | (u0 >> 16);
}
static __device__ __forceinline__ uint32_t pack_lo2(float f0, float f1) {
    uint32_t u0 = __float_as_uint(f0), u1 = __float_as_uint(f1);
    float l0 = f0 - __uint_as_float(u0 & 0xFFFF0000u);
    float l1 = f1 - __uint_as_float(u1 & 0xFFFF0000u);
    uint32_t v0 = __float_as_uint(l0), v1 = __float_as_uint(l1);
    return (v1 & 0xFFFF0000u) | (v0 >> 16);
}

// C/D 32x32 frag row for reg, half=lane>>5 (m74/m101-verified layout)
#define R32(reg, half) (((reg) & 3) + 8 * ((reg) >> 2) + 4 * (half))

// ---------------------------------------------------------------------------
// Kernel 1: Q = X @ W via hi/lo-split bf16 MFMA (3 products: hh, hl, lh).
// Block tile 128x128, 4 waves (2x2), wave tile 64x64, BK=32.
// XCD swizzle: 1D grid 1536; same-row-slab blocks co-located on one XCD.
// Epilogue writes Q into d_out in the grouped-split format K2 consumes:
// per row, 96 groups of [16B hi-bf16 x8 | 16B lo-bf16 x8] = 3072 B/row.
// ---------------------------------------------------------------------------
__global__ __launch_bounds__(256, 2) void gemm_xw_mfma(const float* __restrict__ X,
                                                       const float* __restrict__ W,
                                                       uint32_t* __restrict__ C) {
    __shared__ __align__(16) unsigned short Ahi[128][40];
    __shared__ __align__(16) unsigned short Alo[128][40];
    __shared__ __align__(16) unsigned short Bhi[128][40];
    __shared__ __align__(16) unsigned short Blo[128][40];

    const int t    = threadIdx.x;
    const int w    = t >> 6;
    const int lane = t & 63;
    const int half = lane >> 5;
    const int ln   = lane & 31;
    const int wi   = w & 1;   // wave M-position (64-row slab)
    const int wh   = w >> 1;  // wave N-position (64-col slab)

    // XCD-aware decode: same M-slab -> same XCD
    const int l   = blockIdx.x;       // 0..1535
    const int xcd = l & 7;
    const int r   = l >> 3;           // 0..191
    const int nx  = r % 6;            // N-tile 0..5
    const int yq  = r / 6;            // 0..31
    const int m0  = (xcd + 8 * yq) * 128;
    const int n0  = nx * 128;

    // A staging: thread owns (row = ar + u*32, float4 col = ac4), u = 0..3
    const int ar  = t >> 3;   // 0..31
    const int ac4 = t & 7;    // 0..7 -> k offset ac4*4
    // B staging: thread owns j-column bj, k range [bkb, bkb+16)
    const int bj  = t & 127;
    const int bkb = (t >> 7) * 16;

    f32x16 acc[2][2];
    f32x16 zf = {};
    #pragma unroll
    for (int is = 0; is < 2; ++is)
        #pragma unroll
        for (int hs = 0; hs < 2; ++hs) acc[is][hs] = zf;

    for (int k0 = 0; k0 < H_; k0 += 32) {
        // ---- issue global loads (overlap with previous tile's compute) ----
        float4 av[4];
        #pragma unroll
        for (int u = 0; u < 4; ++u)
            av[u] = *(const float4*)&X[(size_t)(m0 + ar + u * 32) * H_ + k0 + ac4 * 4];
        const float* wp = W + (size_t)(k0 + bkb) * H_ + n0 + bj;
        float wv[16];
        #pragma unroll
        for (int kk = 0; kk < 16; ++kk)
            wv[kk] = wp[(size_t)kk * H_];

        // ---- pack to hi/lo bf16 in registers ----
        uint2 ahp[4], alp[4];
        #pragma unroll
        for (int u = 0; u < 4; ++u) {
            ahp[u] = make_uint2(pack_hi2(av[u].x, av[u].y), pack_hi2(av[u].z, av[u].w));
            alp[u] = make_uint2(pack_lo2(av[u].x, av[u].y), pack_lo2(av[u].z, av[u].w));
        }
        uint4 bhp[2], blp[2];
        #pragma unroll
        for (int q = 0; q < 2; ++q) {
            const int b8 = q * 8;
            bhp[q] = make_uint4(pack_hi2(wv[b8 + 0], wv[b8 + 1]), pack_hi2(wv[b8 + 2], wv[b8 + 3]),
                                pack_hi2(wv[b8 + 4], wv[b8 + 5]), pack_hi2(wv[b8 + 6], wv[b8 + 7]));
            blp[q] = make_uint4(pack_lo2(wv[b8 + 0], wv[b8 + 1]), pack_lo2(wv[b8 + 2], wv[b8 + 3]),
                                pack_lo2(wv[b8 + 4], wv[b8 + 5]), pack_lo2(wv[b8 + 6], wv[b8 + 7]));
        }

        __syncthreads();   // previous tile's readers done
        #pragma unroll
        for (int u = 0; u < 4; ++u) {
            *(uint2*)&Ahi[ar + u * 32][ac4 * 4] = ahp[u];
            *(uint2*)&Alo[ar + u * 32][ac4 * 4] = alp[u];
        }
        #pragma unroll
        for (int q = 0; q < 2; ++q) {
            *(uint4*)&Bhi[bj][bkb + q * 8] = bhp[q];
            *(uint4*)&Blo[bj][bkb + q * 8] = blp[q];
        }
        __syncthreads();   // tile staged

        // ---- MFMA inner loop: 2 k16 steps, 12 MFMA each per wave ----
        #pragma unroll
        for (int ks = 0; ks < 2; ++ks) {
            const int koff = ks * 16 + half * 8;
            bf16x8 ah[2], al[2], bh[2], bl[2];
            #pragma unroll
            for (int is = 0; is < 2; ++is) {
                ah[is] = *(const bf16x8*)&Ahi[wi * 64 + is * 32 + ln][koff];
                al[is] = *(const bf16x8*)&Alo[wi * 64 + is * 32 + ln][koff];
            }
            #pragma unroll
            for (int hs = 0; hs < 2; ++hs) {
                bh[hs] = *(const bf16x8*)&Bhi[wh * 64 + hs * 32 + ln][koff];
                bl[hs] = *(const bf16x8*)&Blo[wh * 64 + hs * 32 + ln][koff];
            }
            #pragma unroll
            for (int is = 0; is < 2; ++is)
                #pragma unroll
                for (int hs = 0; hs < 2; ++hs) {
                    acc[is][hs] = mfma32(ah[is], bh[hs], acc[is][hs]);
                    acc[is][hs] = mfma32(ah[is], bl[hs], acc[is][hs]);
                    acc[is][hs] = mfma32(al[is], bh[hs], acc[is][hs]);
                }
        }
    }

    // ---- epilogue: fp32 acc -> grouped hi/lo split format ----
    #pragma unroll
    for (int is = 0; is < 2; ++is)
        #pragma unroll
        for (int hs = 0; hs < 2; ++hs)
            #pragma unroll
            for (int reg = 0; reg < 16; ++reg) {
                float v  = acc[is][hs][reg];
                float v1 = __shfl_xor(v, 1);
                if ((ln & 1) == 0) {
                    const int gi = m0 + wi * 64 + is * 32 + R32(reg, half);
                    const int gj = n0 + wh * 64 + hs * 32 + ln;   // even
                    uint32_t* orow = C + (size_t)gi * H_;         // 768 u32/row
                    const int g = gj >> 3;
                    const int p = (gj >> 1) & 3;
                    orow[g * 8 + p]     = pack_hi2(v, v1);
                    orow[g * 8 + 4 + p] = pack_lo2(v, v1);
                }
            }
}

// ---------------------------------------------------------------------------
// Kernel 2 (RESTRUCTURED): scores + softmax -> normalized P (bf16) in ws.
// Block = 64 i-rows, 4 waves, grid 512 (XCD swizzle: same batch -> same XCD).
// Loop order: kph outer (12 x 64k), jb inner (4 x 128j).
//   - Q chunk (64 rows x 64 k, grouped-split) staged to LDS once per kph:
//     compute section is LDS-only (no global latency), Q traffic /4.
//   - K slab (128 j x 64 k) re-packed hi/lo per (kph,jb); next phase's 8
//     float4 X-loads issued BEFORE compute (T14): HBM latency hides under
//     MFMA. Accumulation order identical to previous version (bit-exact).
// ---------------------------------------------------------------------------
__global__ __launch_bounds__(256, 2) void attn_scores(const float* __restrict__ X,
                                                      const uint32_t* __restrict__ Q32,
                                                      const float* __restrict__ bias_p,
                                                      __hip_bfloat16* __restrict__ P) {
    __shared__ __align__(16) unsigned short Khi[128][72];   // stride 144B: banks 4*r%32
    __shared__ __align__(16) unsigned short Klo[128][72];
    __shared__ __align__(16) unsigned short Qs[64][136];    // 8 grp x (8 hi | 8 lo) u16, stride 272B
    __shared__ float smax[4][64];
    __shared__ float ssum[4][64];
    __shared__ float sscale[4][64];

    const int t    = threadIdx.x;
    const int w    = t >> 6;
    const int lane = t & 63;
    const int half = lane >> 5;
    const int ln   = lane & 31;

    // XCD-aware decode: same batch -> same XCD
    const int l  = blockIdx.x;        // 0..511
    const int q  = l >> 3;            // 0..63
    const int b  = (l & 7) + 8 * (q >> 3);
    const int I0 = (q & 7) * 64;
    const float bias = bias_p[0];

    const float* xb = X + (size_t)b * N_ * H_;
    const uint32_t* qbase = Q32 + ((size_t)b * N_ + I0) * H_;

    // K staging map: thread t covers idx = t + 256u (u 0..7):
    //   row kr(u) = (t>>4) + 16u, float4-col kc4 = t & 15  (coalesced 256B/16 lanes)
    const int krb = t >> 4;   // base row 0..15
    const int kc4 = t & 15;   // 0..15 -> k offset kc4*4 within 64-k chunk

    f32x16 acc[2][4];
    f32x16 zf = {};
    #pragma unroll
    for (int is = 0; is < 2; ++is)
        #pragma unroll
        for (int jb = 0; jb < 4; ++jb) acc[is][jb] = zf;

    float4 kv[8];
    // prologue: prefetch K regs for phase 0 (kph=0, jb=0)
    #pragma unroll
    for (int u = 0; u < 8; ++u)
        kv[u] = *(const float4*)&xb[(size_t)(krb + 16 * u) * H_ + kc4 * 4];

    for (int kph = 0; kph < 12; ++kph) {
        #pragma unroll
        for (int jb = 0; jb < 4; ++jb) {
            // ---- pack prefetched K to hi/lo (register-only) ----
            uint2 hp[8], lp[8];
            #pragma unroll
            for (int u = 0; u < 8; ++u) {
                hp[u] = make_uint2(pack_hi2(kv[u].x, kv[u].y), pack_hi2(kv[u].z, kv[u].w));
                lp[u] = make_uint2(pack_lo2(kv[u].x, kv[u].y), pack_lo2(kv[u].z, kv[u].w));
            }
            __syncthreads();   // previous phase's LDS readers done
            #pragma unroll
            for (int u = 0; u < 8; ++u) {
                *(uint2*)&Khi[krb + 16 * u][kc4 * 4] = hp[u];
                *(uint2*)&Klo[krb + 16 * u][kc4 * 4] = lp[u];
            }
            if (jb == 0) {
                // ---- stage Q chunk for this kph: 64 rows x 16 uint4 ----
                uint32_t* qlds = (uint32_t*)&Qs[0][0];
                #pragma unroll
                for (int u = 0; u < 4; ++u) {
                    const int r   = (t >> 4) + 16 * u;
                    const int w16 = t & 15;
                    uint4 v = *(const uint4*)&qbase[(size_t)r * H_ + kph * 64 + w16 * 4];
                    *(uint4*)&qlds[r * 68 + w16 * 4] = v;
                }
            }
            __syncthreads();   // K (and Q) staged

            // ---- issue K prefetch for the NEXT phase (hides under MFMA) ----
            {
                const int np = kph * 4 + jb + 1;
                if (np < 48) {
                    const int nk = np >> 2, nj = np & 3;
                    #pragma unroll
                    for (int u = 0; u < 8; ++u)
                        kv[u] = *(const float4*)&xb[(size_t)(nj * 128 + krb + 16 * u) * H_ +
                                                    nk * 64 + kc4 * 4];
                }
            }

            // ---- compute: 4 k16 steps, LDS-only operands ----
            #pragma unroll
            for (int ks = 0; ks < 4; ++ks) {
                const int gq = ks * 2 + half;       // Q group within chunk
                bf16x8 qh[2], ql[2];
                #pragma unroll
                for (int is = 0; is < 2; ++is) {
                    qh[is] = *(const bf16x8*)&Qs[is * 32 + ln][gq * 16];
                    ql[is] = *(const bf16x8*)&Qs[is * 32 + ln][gq * 16 + 8];
                }
                const int koff = ks * 16 + half * 8;
                bf16x8 kh = *(const bf16x8*)&Khi[w * 32 + ln][koff];
                bf16x8 kl = *(const bf16x8*)&Klo[w * 32 + ln][koff];
                #pragma unroll
                for (int is = 0; is < 2; ++is) {
                    acc[is][jb] = mfma32(qh[is], kh, acc[is][jb]);
                    acc[is][jb] = mfma32(qh[is], kl, acc[is][jb]);
                    acc[is][jb] = mfma32(ql[is], kh, acc[is][jb]);
                }
            }
        }
    }

    // bias + diagonal zero (ref zeroes scores at i==j AFTER bias, pre-softmax)
    const int gj = w * 32 + ln;  // + jb*128
    #pragma unroll
    for (int is = 0; is < 2; ++is)
        #pragma unroll
        for (int jb = 0; jb < 4; ++jb)
            #pragma unroll
            for (int reg = 0; reg < 16; ++reg) {
                float v = acc[is][jb][reg] + bias;
                int gi = I0 + is * 32 + R32(reg, half);
                if (gi == jb * 128 + gj) v = 0.0f;
                acc[is][jb][reg] = v;
            }

    // wave-local row max over this wave's 128 j
    float mrow[2][16];
    #pragma unroll
    for (int is = 0; is < 2; ++is)
        #pragma unroll
        for (int reg = 0; reg < 16; ++reg) {
            float m = acc[is][0][reg];
            #pragma unroll
            for (int jb = 1; jb < 4; ++jb) m = fmaxf(m, acc[is][jb][reg]);
            #pragma unroll
            for (int d = 1; d < 32; d <<= 1) m = fmaxf(m, __shfl_xor(m, d));
            mrow[is][reg] = m;
            if (ln == 0) smax[w][is * 32 + R32(reg, half)] = m;
        }

    // exp + wave-local row sum
    #pragma unroll
    for (int is = 0; is < 2; ++is)
        #pragma unroll
        for (int reg = 0; reg < 16; ++reg) {
            float s = 0.f;
            #pragma unroll
            for (int jb = 0; jb < 4; ++jb) {
                float e = __expf(acc[is][jb][reg] - mrow[is][reg]);
                acc[is][jb][reg] = e;
                s += e;
            }
            #pragma unroll
            for (int d = 1; d < 32; d <<= 1) s += __shfl_xor(s, d);
            if (ln == 0) ssum[w][is * 32 + R32(reg, half)] = s;
        }
    __syncthreads();

    // combine across the 4 waves; sscale[w][row] = exp(m_w - M) / L
    if (t < 64) {
        float M = smax[0][t];
        #pragma unroll
        for (int w2 = 1; w2 < 4; ++w2) M = fmaxf(M, smax[w2][t]);
        float L = 0.f;
        #pragma unroll
        for (int w2 = 0; w2 < 4; ++w2) L += ssum[w2][t] * __expf(smax[w2][t] - M);
        float invL = 1.0f / L;
        #pragma unroll
        for (int w2 = 0; w2 < 4; ++w2) sscale[w2][t] = __expf(smax[w2][t] - M) * invL;
    }
    __syncthreads();

    // store normalized P (bf16) to ws
    __hip_bfloat16* Pb = P + (size_t)b * N_ * N_;
    #pragma unroll
    for (int is = 0; is < 2; ++is)
        #pragma unroll
        for (int reg = 0; reg < 16; ++reg) {
            int row = is * 32 + R32(reg, half);
            float sc = sscale[w][row];
            #pragma unroll
            for (int jb = 0; jb < 4; ++jb) {
                float p = acc[is][jb][reg] * sc;
                Pb[(size_t)(I0 + row) * N_ + jb * 128 + w * 32 + ln] = __float2bfloat16(p);
            }
        }
}

// ---------------------------------------------------------------------------
// Kernel 3: O = P (bf16) @ X (bf16 RNE), MFMA 32x32x16. Block tile 128i x 256h,
// wave tile 64i x 128h. X tile transposed into LDS (h-major, stride 40 bf16).
// XCD swizzle: 1D grid 768; the 12 blocks of a batch co-located on one XCD.
// ---------------------------------------------------------------------------
__global__ __launch_bounds__(256, 2) void pv_gemm(const float* __restrict__ X,
                                                  const __hip_bfloat16* __restrict__ P,
                                                  float* __restrict__ O) {
    __shared__ __align__(16) unsigned short Pt[128][40];
    __shared__ __align__(16) unsigned short Vt[256][40];

    const int t    = threadIdx.x;
    const int w    = t >> 6;
    const int lane = t & 63;
    const int half = lane >> 5;
    const int ln   = lane & 31;
    const int wi   = w & 1;
    const int wh   = w >> 1;

    // XCD-aware decode: same batch -> same XCD
    const int l     = blockIdx.x;     // 0..767
    const int r     = l >> 3;         // 0..95
    const int inner = r % 12;
    const int b     = (l & 7) + 8 * (r / 12);
    const int H0    = (inner % 3) * 256;
    const int I0    = (inner / 3) * 128;

    const unsigned short* Pb = (const unsigned short*)P + (size_t)b * N_ * N_;
    const float* xb = X + (size_t)b * N_ * H_;

    f32x16 acc[2][4];
    f32x16 zf = {};
    #pragma unroll
    for (int is = 0; is < 2; ++is)
        #pragma unroll
        for (int hs = 0; hs < 4; ++hs) acc[is][hs] = zf;

    for (int j0 = 0; j0 < N_; j0 += 32) {
        __syncthreads();
        // stage P tile 128 x 32 (row-major, already bf16)
        #pragma unroll
        for (int u = 0; u < 2; ++u) {
            int idx = t + 256 * u;
            int rr  = idx >> 2;
            int c8  = idx & 3;
            uint4 v = *(const uint4*)&Pb[(size_t)(I0 + rr) * N_ + j0 + c8 * 8];
            *(uint4*)&Pt[rr][c8 * 8] = v;
        }
        // stage V tile transposed: thread t owns h-col H0+t, walks 32 j-rows
        {
            const float* xc = xb + (size_t)j0 * H_ + H0 + t;
            #pragma unroll
            for (int jj = 0; jj < 32; jj += 2) {
                float f0 = xc[(size_t)jj * H_];
                float f1 = xc[(size_t)(jj + 1) * H_];
                __hip_bfloat16 b0 = __float2bfloat16(f0);
                __hip_bfloat16 b1 = __float2bfloat16(f1);
                unsigned short u0, u1;
                __builtin_memcpy(&u0, &b0, 2);
                __builtin_memcpy(&u1, &b1, 2);
                *(uint32_t*)&Vt[t][jj] = ((uint32_t)u1 << 16) | u0;
            }
        }
        __syncthreads();
        #pragma unroll
        for (int ks = 0; ks < 2; ++ks) {
            const int koff = ks * 16 + half * 8;
            bf16x8 a[2], v[4];
            #pragma unroll
            for (int is = 0; is < 2; ++is)
                a[is] = *(const bf16x8*)&Pt[wi * 64 + is * 32 + ln][koff];
            #pragma unroll
            for (int hs = 0; hs < 4; ++hs)
                v[hs] = *(const bf16x8*)&Vt[wh * 128 + hs * 32 + ln][koff];
            #pragma unroll
            for (int is = 0; is < 2; ++is)
                #pragma unroll
                for (int hs = 0; hs < 4; ++hs)
                    acc[is][hs] = mfma32(a[is], v[hs], acc[is][hs]);
        }
    }

    float* Ob = O + (size_t)b * N_ * H_;
    #pragma unroll
    for (int is = 0; is < 2; ++is)
        #pragma unroll
        for (int hs = 0; hs < 4; ++hs)
            #pragma unroll
            for (int reg = 0; reg < 16; ++reg) {
                int row = I0 + wi * 64 + is * 32 + R32(reg, half);
                int col = H0 + wh * 128 + hs * 32 + ln;
                Ob[(size_t)row * H_ + col] = acc[is][hs][reg];
            }
}

extern "C" void kernel_launch(void* const* d_in, const int* in_sizes, int n_in,
                              void* d_out, int out_size, void* d_ws, size_t ws_size,
                              hipStream_t stream) {
    const float* x    = (const float*)d_in[0];   // [B,N,H]
    const float* W    = (const float*)d_in[1];   // [H,H]
    const float* bias = (const float*)d_in[2];   // [1]

    // K1: d_out <- split(X @ W) via hi/lo bf16 MFMA (grouped format, fp32 footprint)
    gemm_xw_mfma<<<dim3(1536), 256, 0, stream>>>(x, W, (uint32_t*)d_out);
    // K2: ws <- normalized softmax(Q . X^T + bias, diag->0)  as bf16 [B,N,N]
    attn_scores<<<dim3(512), 256, 0, stream>>>(
        x, (const uint32_t*)d_out, bias, (__hip_bfloat16*)d_ws);
    // K3: d_out <- P @ X  (fp32 result)
    pv_gemm<<<dim3(768), 256, 0, stream>>>(
        x, (const __hip_bfloat16*)d_ws, (float*)d_out);
}